// Round 2
// baseline (217.724 us; speedup 1.0000x reference)
//
#include <hip/hip_runtime.h>
#include <math.h>

#define B   8
#define NA  33600
#define M   64
#define NC  80
#define KK  13
#define EPSF 1e-9f
#define PIF 3.14159265358979323846f

#define NPOS 1536          // per-(b,m) candidate capacity (max in-circle ~1160)
#define CHUNK 256

// ---------------------------------------------------------------- helpers

__device__ __forceinline__ float circle_iou(float gx, float gy, float gr,
                                            float px, float py, float pr) {
    float dx = gx - px, dy = gy - py;
    float d  = sqrtf(dx * dx + dy * dy + 1e-12f);
    float r0sq = gr * gr, r1sq = pr * pr;
    float d1 = (r0sq - r1sq + d * d) / (2.0f * d);
    float d2 = d - d1;
    float t0 = fminf(fmaxf(d1 / fmaxf(gr, EPSF), -1.0f), 1.0f);
    float t1 = fminf(fmaxf(d2 / fmaxf(pr, EPSF), -1.0f), 1.0f);
    float a0 = r0sq * acosf(t0) - d1 * sqrtf(fmaxf(r0sq - d1 * d1, 0.0f));
    float a1 = r1sq * acosf(t1) - d2 * sqrtf(fmaxf(r1sq - d2 * d2, 0.0f));
    float lens = a0 + a1;
    float rmin = fminf(gr, pr);
    float contained = PIF * rmin * rmin;
    float inter = (d >= gr + pr) ? 0.0f
                : ((d <= fabsf(gr - pr)) ? contained : lens);
    float uni = PIF * r0sq + PIF * r1sq - inter;
    return (uni > 0.0f) ? inter / uni : 0.0f;
}

// masked overlap + align_metric for one (b, gt, anchor) — identical formula everywhere
__device__ __forceinline__ void ov_met(const float* __restrict__ pd_scores,
                                       const float* __restrict__ pd_circles,
                                       const float* __restrict__ anc,
                                       int b, int a,
                                       float gx, float gy, float gr, int gl, float gmask,
                                       float* ov_out, float* met_out) {
    float ax = anc[2 * a], ay = anc[2 * a + 1];
    float dx = ax - gx, dy = ay - gy;
    float dan = sqrtf(dx * dx + dy * dy);
    float ov = 0.0f, met = 0.0f;
    if (gmask > 0.0f && dan < gr) {
        int base = (b * NA + a) * 3;
        float px = pd_circles[base + 0];
        float py = pd_circles[base + 1];
        float pr = pd_circles[base + 2];
        float iou = circle_iou(gx, gy, gr, px, py, pr);
        ov = iou * gmask;
        float sc = pd_scores[(size_t)(b * NA + a) * NC + gl] * gmask;
        float o2 = ov * ov;
        met = sc * (o2 * o2 * o2);              // score^1 * ov^6
    }
    *ov_out = ov; *met_out = met;
}

// ---------------------------------------------------------------- K0 init

__global__ void k_init(int* __restrict__ fg_count, int* __restrict__ sel_m,
                       int* __restrict__ pos_align_i, int* __restrict__ pos_ov_i,
                       int* __restrict__ bm_cnt) {
    int i = blockIdx.x * blockDim.x + threadIdx.x;
    if (i < B * NA) { fg_count[i] = 0; sel_m[i] = 0x7fffffff; }
    if (i < B * M)  { pos_align_i[i] = 0; pos_ov_i[i] = 0; bm_cnt[i] = 0; }
}

// ---------------------------------------------------------------- K1a: dense hit detection
// one thread per (b, anchor); loop over 64 gts held in LDS; append in-circle hits.

__global__ __launch_bounds__(CHUNK)
void k1a_hits(const float* __restrict__ anc, const float* __restrict__ gt_circles,
              const float* __restrict__ mask_gt,
              int* __restrict__ bm_cnt, int* __restrict__ cand_a) {
    int b   = blockIdx.y;
    int tid = threadIdx.x;
    __shared__ float s_gx[M], s_gy[M], s_gr[M];
    __shared__ int   s_act[M];
    if (tid < M) {
        int gi = b * M + tid;
        s_act[tid] = mask_gt[gi] > 0.0f;
        s_gx[tid] = gt_circles[gi * 3 + 0];
        s_gy[tid] = gt_circles[gi * 3 + 1];
        s_gr[tid] = gt_circles[gi * 3 + 2];
    }
    __syncthreads();

    int a = blockIdx.x * CHUNK + tid;
    float ax = 0.f, ay = 0.f;
    bool valid = a < NA;
    if (valid) {
        float2 p = reinterpret_cast<const float2*>(anc)[a];
        ax = p.x; ay = p.y;
    }
    for (int m = 0; m < M; m++) {
        if (!s_act[m]) continue;                 // wave-uniform branch
        float dx = ax - s_gx[m], dy = ay - s_gy[m];
        bool hit = valid && (sqrtf(dx * dx + dy * dy) < s_gr[m]);
        if (hit) {
            int bm = b * M + m;                  // wave-uniform address -> aggregated atomic
            int pos = atomicAdd(&bm_cnt[bm], 1);
            if (pos < NPOS) cand_a[bm * NPOS + pos] = a;
        }
    }
}

// ---------------------------------------------------------------- K1c: per-(b,m) metric + top-13

__global__ __launch_bounds__(256)
void k1c_topk(const float* __restrict__ pd_scores, const float* __restrict__ pd_circles,
              const float* __restrict__ anc, const int* __restrict__ gt_labels,
              const float* __restrict__ gt_circles, const float* __restrict__ mask_gt,
              const int* __restrict__ bm_cnt, const int* __restrict__ cand_a,
              int* __restrict__ topk_a) {
    int bm = blockIdx.x;
    int b  = bm / M;
    int tid = threadIdx.x;
    __shared__ int   s_a[NPOS];
    __shared__ float s_v[NPOS];
    __shared__ float r_val[256];
    __shared__ int   r_anc[256];
    __shared__ int   r_pos[256];
    __shared__ int   s_win[KK];

    float gmask = mask_gt[bm];
    if (!(gmask > 0.0f)) {
        if (tid < KK) topk_a[bm * KK + tid] = -1;
        return;
    }
    float gx = gt_circles[bm * 3 + 0];
    float gy = gt_circles[bm * 3 + 1];
    float gr = gt_circles[bm * 3 + 2];
    int gl = gt_labels[bm];
    gl = gl < 0 ? 0 : (gl > NC - 1 ? NC - 1 : gl);

    int cnt = bm_cnt[bm]; if (cnt > NPOS) cnt = NPOS;

    // dense metric computation over candidate list (every lane busy)
    for (int i = tid; i < cnt; i += 256) {
        int a = cand_a[bm * NPOS + i];
        float ov, met;
        ov_met(pd_scores, pd_circles, anc, b, a, gx, gy, gr, gl, gmask, &ov, &met);
        s_a[i] = a; s_v[i] = met;
    }
    __syncthreads();

    // 13 rounds of argmax (val desc, anchor-index asc) == lax.top_k order
    for (int k = 0; k < KK; k++) {
        float bv = 0.0f; int ba = 0x7fffffff; int bp = -1;
        for (int i = tid; i < cnt; i += 256) {
            float v = s_v[i];
            if (v > 0.0f) {                       // zero-metric entries are fill-only
                int a = s_a[i];
                if (v > bv || (v == bv && a < ba)) { bv = v; ba = a; bp = i; }
            }
        }
        r_val[tid] = bv; r_anc[tid] = ba; r_pos[tid] = bp;
        __syncthreads();
        for (int s = 128; s > 0; s >>= 1) {
            if (tid < s) {
                float v2 = r_val[tid + s]; int a2 = r_anc[tid + s];
                if (v2 > r_val[tid] || (v2 == r_val[tid] && a2 < r_anc[tid])) {
                    r_val[tid] = v2; r_anc[tid] = a2; r_pos[tid] = r_pos[tid + s];
                }
            }
            __syncthreads();
        }
        if (tid == 0) {
            if (r_pos[0] >= 0) { s_win[k] = r_anc[0]; s_v[r_pos[0]] = -1.0f; }
            else s_win[k] = -2;                   // needs zero-fill
        }
        __syncthreads();
    }

    // zero-fill: top_k ties at 0 pick lowest anchor indices with metric == 0
    if (tid == 0) {
        int a = 0;
        for (int k = 0; k < KK; k++) {
            if (s_win[k] == -2) {
                s_win[k] = -1;
                while (a < NA) {
                    float ov, met;
                    ov_met(pd_scores, pd_circles, anc, b, a, gx, gy, gr, gl, gmask, &ov, &met);
                    int take = !(met > 0.0f);
                    if (take) { s_win[k] = a; a++; break; }
                    a++;
                }
            }
        }
    }
    __syncthreads();

    // winners enter mask_pos only if anchor center inside the gt circle
    if (tid < KK) {
        int a = s_win[tid];
        int out = -1;
        if (a >= 0) {
            float ax = anc[2 * a], ay = anc[2 * a + 1];
            float dx = ax - gx, dy = ay - gy;
            if (sqrtf(dx * dx + dy * dy) < gr) out = a;
        }
        topk_a[bm * KK + tid] = out;
    }
}

// ---------------------------------------------------------------- K2 scatter

__global__ void k_scatter(const int* __restrict__ topk_a,
                          int* __restrict__ fg_count, int* __restrict__ sel_m) {
    int i = blockIdx.x * blockDim.x + threadIdx.x;
    if (i >= B * M * KK) return;
    int a = topk_a[i];
    if (a < 0) return;
    int bm = i / KK;
    int b = bm / M, m = bm % M;
    atomicAdd(&fg_count[b * NA + a], 1);
    atomicMin(&sel_m[b * NA + a], m);
}

// ---------------------------------------------------------------- K3+K4 fused: per-anchor resolve + pos maxima

__global__ void k_resolve_posmax(const float* __restrict__ pd_scores,
                                 const float* __restrict__ pd_circles, const float* __restrict__ anc,
                                 const int* __restrict__ gt_labels, const float* __restrict__ gt_circles,
                                 const float* __restrict__ mask_gt,
                                 const int* __restrict__ fg_count, const int* __restrict__ sel_m,
                                 int* __restrict__ assigned, float* __restrict__ am_val,
                                 int* __restrict__ pos_align_i, int* __restrict__ pos_ov_i,
                                 float* __restrict__ out_labels, float* __restrict__ out_circles,
                                 float* __restrict__ out_fg, float* __restrict__ out_gtidx) {
    int i = blockIdx.x * blockDim.x + threadIdx.x;
    if (i >= B * NA) return;
    int b = i / NA, a = i - b * NA;
    int c = fg_count[i];
    int g = 0, fg = 0;
    if (c == 1) { g = sel_m[i]; fg = 1; }
    else if (c > 1) {
        // jnp.argmax over masked overlaps, lowest index wins ties
        float ax = anc[2 * a], ay = anc[2 * a + 1];
        int pbase = i * 3;
        float px = pd_circles[pbase], py = pd_circles[pbase + 1], pr = pd_circles[pbase + 2];
        float best = -1.0f; int bmx = 0;
        for (int m = 0; m < M; m++) {
            float gmask = mask_gt[b * M + m];
            float gx = gt_circles[(b * M + m) * 3 + 0];
            float gy = gt_circles[(b * M + m) * 3 + 1];
            float grr = gt_circles[(b * M + m) * 3 + 2];
            float dx = ax - gx, dy = ay - gy;
            float ov = 0.0f;
            if (gmask > 0.0f && sqrtf(dx * dx + dy * dy) < grr)
                ov = circle_iou(gx, gy, grr, px, py, pr) * gmask;
            if (ov > best) { best = ov; bmx = m; }
        }
        g = bmx; fg = 1;
    }
    assigned[i] = fg ? g : -1;
    int lbl = gt_labels[b * M + g]; if (lbl < 0) lbl = 0;   // clip(.., 0, None)
    out_labels[i] = (float)lbl;
    out_circles[(size_t)i * 3 + 0] = gt_circles[(b * M + g) * 3 + 0];
    out_circles[(size_t)i * 3 + 1] = gt_circles[(b * M + g) * 3 + 1];
    out_circles[(size_t)i * 3 + 2] = gt_circles[(b * M + g) * 3 + 2];
    out_fg[i]    = fg ? 1.0f : 0.0f;
    out_gtidx[i] = (float)g;

    // pos_align / pos_overlaps contribution (only assigned anchors)
    if (!fg) { am_val[i] = 0.0f; return; }
    float gmask = mask_gt[b * M + g];
    float gx = gt_circles[(b * M + g) * 3 + 0];
    float gy = gt_circles[(b * M + g) * 3 + 1];
    float grc = gt_circles[(b * M + g) * 3 + 2];
    int gl2 = gt_labels[b * M + g];
    gl2 = gl2 < 0 ? 0 : (gl2 > NC - 1 ? NC - 1 : gl2);
    float ov, met;
    ov_met(pd_scores, pd_circles, anc, b, a, gx, gy, grc, gl2, gmask, &ov, &met);
    am_val[i] = met;
    atomicMax(&pos_align_i[b * M + g], __float_as_int(met));  // values >= 0
    atomicMax(&pos_ov_i[b * M + g],    __float_as_int(ov));
}

// ---------------------------------------------------------------- K5 target_scores (86 MB write)

__global__ void k_scores(const int* __restrict__ assigned, const float* __restrict__ am_val,
                         const int* __restrict__ pos_align_i, const int* __restrict__ pos_ov_i,
                         const int* __restrict__ gt_labels,
                         float* __restrict__ out_scores) {
    int q = blockIdx.x * blockDim.x + threadIdx.x;      // one float4 per thread
    if (q >= (B * NA * NC) / 4) return;
    int idx = q * 4;
    int row = idx / NC;
    int c0  = idx - row * NC;
    float4 v = make_float4(0.f, 0.f, 0.f, 0.f);
    int g = assigned[row];
    if (g >= 0) {
        int b = row / NA;
        float pa = __int_as_float(pos_align_i[b * M + g]);
        float po = __int_as_float(pos_ov_i[b * M + g]);
        float norm = am_val[row] * po / (pa + EPSF);
        int lbl = gt_labels[b * M + g]; if (lbl < 0) lbl = 0;
        int off = lbl - c0;
        if (off >= 0 && off < 4) ((float*)&v)[off] = norm;
    }
    reinterpret_cast<float4*>(out_scores)[q] = v;
}

// ---------------------------------------------------------------- launch

extern "C" void kernel_launch(void* const* d_in, const int* in_sizes, int n_in,
                              void* d_out, int out_size, void* d_ws, size_t ws_size,
                              hipStream_t stream) {
    const float* pd_scores  = (const float*)d_in[0];   // (B, NA, NC)
    const float* pd_circles = (const float*)d_in[1];   // (B, NA, 3)
    const float* anc        = (const float*)d_in[2];   // (NA, 2)
    const int*   gt_labels  = (const int*)  d_in[3];   // (B, M, 1)
    const float* gt_circles = (const float*)d_in[4];   // (B, M, 3)
    const float* mask_gt    = (const float*)d_in[5];   // (B, M, 1)

    // workspace layout
    char* w = (char*)d_ws;
    int*   cand_a      = (int*)w;   w += (size_t)B * M * NPOS * sizeof(int);  // 3 MB
    int*   bm_cnt      = (int*)w;   w += (size_t)B * M * sizeof(int);
    int*   topk        = (int*)w;   w += (size_t)B * M * KK * sizeof(int);
    int*   fg_count    = (int*)w;   w += (size_t)B * NA * sizeof(int);
    int*   sel_m       = (int*)w;   w += (size_t)B * NA * sizeof(int);
    int*   assigned    = (int*)w;   w += (size_t)B * NA * sizeof(int);
    float* am_val      = (float*)w; w += (size_t)B * NA * sizeof(float);
    int*   pos_align_i = (int*)w;   w += (size_t)B * M * sizeof(int);
    int*   pos_ov_i    = (int*)w;   w += (size_t)B * M * sizeof(int);

    // output layout (concat in return order, float32)
    float* out        = (float*)d_out;
    float* out_labels = out;                              // B*NA
    float* out_circ   = out_labels + (size_t)B * NA;      // B*NA*3
    float* out_scores = out_circ + (size_t)B * NA * 3;    // B*NA*NC
    float* out_fg     = out_scores + (size_t)B * NA * NC; // B*NA
    float* out_gtidx  = out_fg + (size_t)B * NA;          // B*NA

    const int T = 256;
    int gBA = (B * NA + T - 1) / T;

    k_init<<<gBA, T, 0, stream>>>(fg_count, sel_m, pos_align_i, pos_ov_i, bm_cnt);

    dim3 g1a((NA + CHUNK - 1) / CHUNK, B);
    k1a_hits<<<g1a, CHUNK, 0, stream>>>(anc, gt_circles, mask_gt, bm_cnt, cand_a);

    k1c_topk<<<B * M, 256, 0, stream>>>(pd_scores, pd_circles, anc, gt_labels,
                                        gt_circles, mask_gt, bm_cnt, cand_a, topk);

    k_scatter<<<(B * M * KK + T - 1) / T, T, 0, stream>>>(topk, fg_count, sel_m);

    k_resolve_posmax<<<gBA, T, 0, stream>>>(pd_scores, pd_circles, anc, gt_labels,
                                            gt_circles, mask_gt, fg_count, sel_m,
                                            assigned, am_val, pos_align_i, pos_ov_i,
                                            out_labels, out_circ, out_fg, out_gtidx);

    int nq = (B * NA * NC) / 4;
    k_scores<<<(nq + T - 1) / T, T, 0, stream>>>(assigned, am_val, pos_align_i, pos_ov_i,
                                                 gt_labels, out_scores);
}

// Round 3
// 139.053 us; speedup vs baseline: 1.5658x; 1.5658x over previous
//
#include <hip/hip_runtime.h>
#include <math.h>

#define B   8
#define NA  33600
#define M   64
#define NC  80
#define KK  13
#define EPSF 1e-9f
#define PIF 3.14159265358979323846f

#define NPOS 1536          // per-(b,m) candidate capacity (max in-circle ~1100)
#define TPB  256

// ---------------------------------------------------------------- helpers

__device__ __forceinline__ float circle_iou(float gx, float gy, float gr,
                                            float px, float py, float pr) {
    float dx = gx - px, dy = gy - py;
    float d  = sqrtf(dx * dx + dy * dy + 1e-12f);
    float r0sq = gr * gr, r1sq = pr * pr;
    float d1 = (r0sq - r1sq + d * d) / (2.0f * d);
    float d2 = d - d1;
    float t0 = fminf(fmaxf(d1 / fmaxf(gr, EPSF), -1.0f), 1.0f);
    float t1 = fminf(fmaxf(d2 / fmaxf(pr, EPSF), -1.0f), 1.0f);
    float a0 = r0sq * acosf(t0) - d1 * sqrtf(fmaxf(r0sq - d1 * d1, 0.0f));
    float a1 = r1sq * acosf(t1) - d2 * sqrtf(fmaxf(r1sq - d2 * d2, 0.0f));
    float lens = a0 + a1;
    float rmin = fminf(gr, pr);
    float contained = PIF * rmin * rmin;
    float inter = (d >= gr + pr) ? 0.0f
                : ((d <= fabsf(gr - pr)) ? contained : lens);
    float uni = PIF * r0sq + PIF * r1sq - inter;
    return (uni > 0.0f) ? inter / uni : 0.0f;
}

// masked overlap + align_metric for one (b, gt, anchor) — identical formula everywhere
__device__ __forceinline__ void ov_met(const float* __restrict__ pd_scores,
                                       const float* __restrict__ pd_circles,
                                       const float* __restrict__ anc,
                                       int b, int a,
                                       float gx, float gy, float gr, int gl, float gmask,
                                       float* ov_out, float* met_out) {
    float ax = anc[2 * a], ay = anc[2 * a + 1];
    float dx = ax - gx, dy = ay - gy;
    float dan = sqrtf(dx * dx + dy * dy);
    float ov = 0.0f, met = 0.0f;
    if (gmask > 0.0f && dan < gr) {
        int base = (b * NA + a) * 3;
        float px = pd_circles[base + 0];
        float py = pd_circles[base + 1];
        float pr = pd_circles[base + 2];
        float iou = circle_iou(gx, gy, gr, px, py, pr);
        ov = iou * gmask;
        float sc = pd_scores[(size_t)(b * NA + a) * NC + gl] * gmask;
        float o2 = ov * ov;
        met = sc * (o2 * o2 * o2);              // score^1 * ov^6
    }
    *ov_out = ov; *met_out = met;
}

// ---------------------------------------------------------------- K0 init

__global__ void k_init(int* __restrict__ fg_count, int* __restrict__ sel_m,
                       int* __restrict__ pos_align_i, int* __restrict__ pos_ov_i) {
    int i = blockIdx.x * blockDim.x + threadIdx.x;
    if (i < B * NA) { fg_count[i] = 0; sel_m[i] = 0x7fffffff; }
    if (i < B * M)  { pos_align_i[i] = 0; pos_ov_i[i] = 0; }
}

// ---------------------------------------------------------------- K1: per-(b,m) compact + metric + top-13 + scatter
// one block per (b,m). LDS-only compaction (distance test only), dense metric,
// shuffle-based argmax, direct atomic scatter of <=13 winners.

__global__ __launch_bounds__(TPB)
void k_topk2(const float* __restrict__ pd_scores, const float* __restrict__ pd_circles,
             const float* __restrict__ anc, const int* __restrict__ gt_labels,
             const float* __restrict__ gt_circles, const float* __restrict__ mask_gt,
             int* __restrict__ fg_count, int* __restrict__ sel_m) {
    int bm = blockIdx.x;
    int b  = bm / M;
    int m  = bm - b * M;
    int tid = threadIdx.x;

    __shared__ int   s_cnt;
    __shared__ int   s_a[NPOS];
    __shared__ float s_v[NPOS];
    __shared__ float w_val[TPB / 64];
    __shared__ int   w_anc[TPB / 64];
    __shared__ int   w_pos[TPB / 64];
    __shared__ int   s_win[KK];

    float gmask = mask_gt[bm];
    if (!(gmask > 0.0f)) return;               // inactive gt contributes nothing

    float gx = gt_circles[bm * 3 + 0];
    float gy = gt_circles[bm * 3 + 1];
    float gr = gt_circles[bm * 3 + 2];
    int gl = gt_labels[bm];
    gl = gl < 0 ? 0 : (gl > NC - 1 ? NC - 1 : gl);

    if (tid == 0) s_cnt = 0;
    __syncthreads();

    // phase A: distance-only scan, compact in-circle anchors into LDS
    for (int a = tid; a < NA; a += TPB) {
        float2 p = reinterpret_cast<const float2*>(anc)[a];
        float dx = p.x - gx, dy = p.y - gy;
        if (sqrtf(dx * dx + dy * dy) < gr) {
            int pos = atomicAdd(&s_cnt, 1);    // LDS atomic — cheap
            if (pos < NPOS) s_a[pos] = a;
        }
    }
    __syncthreads();
    int cnt = s_cnt; if (cnt > NPOS) cnt = NPOS;

    // phase B: dense metric over candidates (full lane utilization)
    for (int i = tid; i < cnt; i += TPB) {
        int a = s_a[i];
        float ov, met;
        ov_met(pd_scores, pd_circles, anc, b, a, gx, gy, gr, gl, gmask, &ov, &met);
        s_v[i] = met;
    }
    __syncthreads();

    // phase C: 13 rounds of argmax (val desc, anchor asc) == lax.top_k order
    for (int k = 0; k < KK; k++) {
        float bv = 0.0f; int ba = 0x7fffffff; int bp = -1;
        for (int i = tid; i < cnt; i += TPB) {
            float v = s_v[i];
            if (v > 0.0f) {                    // zero-metric entries are fill-only
                int a = s_a[i];
                if (v > bv || (v == bv && a < ba)) { bv = v; ba = a; bp = i; }
            }
        }
        // wave butterfly
        for (int off = 32; off > 0; off >>= 1) {
            float v2 = __shfl_xor(bv, off);
            int   a2 = __shfl_xor(ba, off);
            int   p2 = __shfl_xor(bp, off);
            if (v2 > bv || (v2 == bv && a2 < ba)) { bv = v2; ba = a2; bp = p2; }
        }
        int w = tid >> 6;
        if ((tid & 63) == 0) { w_val[w] = bv; w_anc[w] = ba; w_pos[w] = bp; }
        __syncthreads();
        if (tid == 0) {
            for (int i = 1; i < TPB / 64; i++) {
                if (w_val[i] > bv || (w_val[i] == bv && w_anc[i] < ba)) {
                    bv = w_val[i]; ba = w_anc[i]; bp = w_pos[i];
                }
            }
            if (bp >= 0) { s_win[k] = ba; s_v[bp] = -1.0f; }
            else s_win[k] = -2;                // needs zero-fill
        }
        __syncthreads();
    }

    // zero-fill: top_k ties at 0 pick lowest anchor indices with metric == 0.
    // met==0 is the overwhelmingly common case, so this walk terminates in ~KK steps.
    if (tid == 0) {
        int a = 0;
        for (int k = 0; k < KK; k++) {
            if (s_win[k] == -2) {
                s_win[k] = -1;
                while (a < NA) {
                    float ov, met;
                    ov_met(pd_scores, pd_circles, anc, b, a, gx, gy, gr, gl, gmask, &ov, &met);
                    int take = !(met > 0.0f);
                    if (take) { s_win[k] = a; a++; break; }
                    a++;
                }
            }
        }
    }
    __syncthreads();

    // winners enter mask_pos only if anchor center inside the gt circle;
    // scatter directly (few, uncontended atomics)
    if (tid < KK) {
        int a = s_win[tid];
        if (a >= 0) {
            float ax = anc[2 * a], ay = anc[2 * a + 1];
            float dx = ax - gx, dy = ay - gy;
            if (sqrtf(dx * dx + dy * dy) < gr) {
                atomicAdd(&fg_count[b * NA + a], 1);
                atomicMin(&sel_m[b * NA + a], m);
            }
        }
    }
}

// ---------------------------------------------------------------- K2 fused: per-anchor resolve + pos maxima

__global__ void k_resolve_posmax(const float* __restrict__ pd_scores,
                                 const float* __restrict__ pd_circles, const float* __restrict__ anc,
                                 const int* __restrict__ gt_labels, const float* __restrict__ gt_circles,
                                 const float* __restrict__ mask_gt,
                                 const int* __restrict__ fg_count, const int* __restrict__ sel_m,
                                 int* __restrict__ assigned, float* __restrict__ am_val,
                                 int* __restrict__ pos_align_i, int* __restrict__ pos_ov_i,
                                 float* __restrict__ out_labels, float* __restrict__ out_circles,
                                 float* __restrict__ out_fg, float* __restrict__ out_gtidx) {
    int i = blockIdx.x * blockDim.x + threadIdx.x;
    if (i >= B * NA) return;
    int b = i / NA, a = i - b * NA;
    int c = fg_count[i];
    int g = 0, fg = 0;
    if (c == 1) { g = sel_m[i]; fg = 1; }
    else if (c > 1) {
        // jnp.argmax over masked overlaps, lowest index wins ties
        float ax = anc[2 * a], ay = anc[2 * a + 1];
        int pbase = i * 3;
        float px = pd_circles[pbase], py = pd_circles[pbase + 1], pr = pd_circles[pbase + 2];
        float best = -1.0f; int bmx = 0;
        for (int mm = 0; mm < M; mm++) {
            float gmask = mask_gt[b * M + mm];
            float gx = gt_circles[(b * M + mm) * 3 + 0];
            float gy = gt_circles[(b * M + mm) * 3 + 1];
            float grr = gt_circles[(b * M + mm) * 3 + 2];
            float dx = ax - gx, dy = ay - gy;
            float ov = 0.0f;
            if (gmask > 0.0f && sqrtf(dx * dx + dy * dy) < grr)
                ov = circle_iou(gx, gy, grr, px, py, pr) * gmask;
            if (ov > best) { best = ov; bmx = mm; }
        }
        g = bmx; fg = 1;
    }
    assigned[i] = fg ? g : -1;
    int lbl = gt_labels[b * M + g]; if (lbl < 0) lbl = 0;   // clip(.., 0, None)
    out_labels[i] = (float)lbl;
    out_circles[(size_t)i * 3 + 0] = gt_circles[(b * M + g) * 3 + 0];
    out_circles[(size_t)i * 3 + 1] = gt_circles[(b * M + g) * 3 + 1];
    out_circles[(size_t)i * 3 + 2] = gt_circles[(b * M + g) * 3 + 2];
    out_fg[i]    = fg ? 1.0f : 0.0f;
    out_gtidx[i] = (float)g;

    if (!fg) { am_val[i] = 0.0f; return; }
    float gmask = mask_gt[b * M + g];
    float gx = gt_circles[(b * M + g) * 3 + 0];
    float gy = gt_circles[(b * M + g) * 3 + 1];
    float grc = gt_circles[(b * M + g) * 3 + 2];
    int gl2 = gt_labels[b * M + g];
    gl2 = gl2 < 0 ? 0 : (gl2 > NC - 1 ? NC - 1 : gl2);
    float ov, met;
    ov_met(pd_scores, pd_circles, anc, b, a, gx, gy, grc, gl2, gmask, &ov, &met);
    am_val[i] = met;
    atomicMax(&pos_align_i[b * M + g], __float_as_int(met));  // values >= 0
    atomicMax(&pos_ov_i[b * M + g],    __float_as_int(ov));
}

// ---------------------------------------------------------------- K3 target_scores (86 MB write)

__global__ void k_scores(const int* __restrict__ assigned, const float* __restrict__ am_val,
                         const int* __restrict__ pos_align_i, const int* __restrict__ pos_ov_i,
                         const int* __restrict__ gt_labels,
                         float* __restrict__ out_scores) {
    int q = blockIdx.x * blockDim.x + threadIdx.x;      // one float4 per thread
    if (q >= (B * NA * NC) / 4) return;
    int idx = q * 4;
    int row = idx / NC;
    int c0  = idx - row * NC;
    float4 v = make_float4(0.f, 0.f, 0.f, 0.f);
    int g = assigned[row];
    if (g >= 0) {
        int b = row / NA;
        float pa = __int_as_float(pos_align_i[b * M + g]);
        float po = __int_as_float(pos_ov_i[b * M + g]);
        float norm = am_val[row] * po / (pa + EPSF);
        int lbl = gt_labels[b * M + g]; if (lbl < 0) lbl = 0;
        int off = lbl - c0;
        if (off >= 0 && off < 4) ((float*)&v)[off] = norm;
    }
    reinterpret_cast<float4*>(out_scores)[q] = v;
}

// ---------------------------------------------------------------- launch

extern "C" void kernel_launch(void* const* d_in, const int* in_sizes, int n_in,
                              void* d_out, int out_size, void* d_ws, size_t ws_size,
                              hipStream_t stream) {
    const float* pd_scores  = (const float*)d_in[0];   // (B, NA, NC)
    const float* pd_circles = (const float*)d_in[1];   // (B, NA, 3)
    const float* anc        = (const float*)d_in[2];   // (NA, 2)
    const int*   gt_labels  = (const int*)  d_in[3];   // (B, M, 1)
    const float* gt_circles = (const float*)d_in[4];   // (B, M, 3)
    const float* mask_gt    = (const float*)d_in[5];   // (B, M, 1)

    // workspace layout
    char* w = (char*)d_ws;
    int*   fg_count    = (int*)w;   w += (size_t)B * NA * sizeof(int);
    int*   sel_m       = (int*)w;   w += (size_t)B * NA * sizeof(int);
    int*   assigned    = (int*)w;   w += (size_t)B * NA * sizeof(int);
    float* am_val      = (float*)w; w += (size_t)B * NA * sizeof(float);
    int*   pos_align_i = (int*)w;   w += (size_t)B * M * sizeof(int);
    int*   pos_ov_i    = (int*)w;   w += (size_t)B * M * sizeof(int);

    // output layout (concat in return order, float32)
    float* out        = (float*)d_out;
    float* out_labels = out;                              // B*NA
    float* out_circ   = out_labels + (size_t)B * NA;      // B*NA*3
    float* out_scores = out_circ + (size_t)B * NA * 3;    // B*NA*NC
    float* out_fg     = out_scores + (size_t)B * NA * NC; // B*NA
    float* out_gtidx  = out_fg + (size_t)B * NA;          // B*NA

    const int T = 256;
    int gBA = (B * NA + T - 1) / T;

    k_init<<<gBA, T, 0, stream>>>(fg_count, sel_m, pos_align_i, pos_ov_i);

    k_topk2<<<B * M, TPB, 0, stream>>>(pd_scores, pd_circles, anc, gt_labels,
                                       gt_circles, mask_gt, fg_count, sel_m);

    k_resolve_posmax<<<gBA, T, 0, stream>>>(pd_scores, pd_circles, anc, gt_labels,
                                            gt_circles, mask_gt, fg_count, sel_m,
                                            assigned, am_val, pos_align_i, pos_ov_i,
                                            out_labels, out_circ, out_fg, out_gtidx);

    int nq = (B * NA * NC) / 4;
    k_scores<<<(nq + T - 1) / T, T, 0, stream>>>(assigned, am_val, pos_align_i, pos_ov_i,
                                                 gt_labels, out_scores);
}

// Round 4
// 105.379 us; speedup vs baseline: 2.0661x; 1.3195x over previous
//
#include <hip/hip_runtime.h>
#include <math.h>

#define B   8
#define NA  33600
#define M   64
#define NC  80
#define KK  13
#define EPSF 1e-9f
#define PIF 3.14159265358979323846f

#define NPOS 1536          // per-(b,m) in-circle capacity (max ~1100 at gt_r=128)
#define TPB  1024          // 16 waves/block, 2 blocks/CU -> full 32 waves/CU

// ---------------------------------------------------------------- helpers

__device__ __forceinline__ float circle_iou(float gx, float gy, float gr,
                                            float px, float py, float pr) {
    float dx = gx - px, dy = gy - py;
    float d  = sqrtf(dx * dx + dy * dy + 1e-12f);
    float r0sq = gr * gr, r1sq = pr * pr;
    float d1 = (r0sq - r1sq + d * d) / (2.0f * d);
    float d2 = d - d1;
    float t0 = fminf(fmaxf(d1 / fmaxf(gr, EPSF), -1.0f), 1.0f);
    float t1 = fminf(fmaxf(d2 / fmaxf(pr, EPSF), -1.0f), 1.0f);
    float a0 = r0sq * acosf(t0) - d1 * sqrtf(fmaxf(r0sq - d1 * d1, 0.0f));
    float a1 = r1sq * acosf(t1) - d2 * sqrtf(fmaxf(r1sq - d2 * d2, 0.0f));
    float lens = a0 + a1;
    float rmin = fminf(gr, pr);
    float contained = PIF * rmin * rmin;
    float inter = (d >= gr + pr) ? 0.0f
                : ((d <= fabsf(gr - pr)) ? contained : lens);
    float uni = PIF * r0sq + PIF * r1sq - inter;
    return (uni > 0.0f) ? inter / uni : 0.0f;
}

// masked overlap + align_metric for one (b, gt, anchor) — identical formula everywhere
__device__ __forceinline__ void ov_met(const float* __restrict__ pd_scores,
                                       const float* __restrict__ pd_circles,
                                       const float* __restrict__ anc,
                                       int b, int a,
                                       float gx, float gy, float gr, int gl, float gmask,
                                       float* ov_out, float* met_out) {
    float ax = anc[2 * a], ay = anc[2 * a + 1];
    float dx = ax - gx, dy = ay - gy;
    float dan = sqrtf(dx * dx + dy * dy);
    float ov = 0.0f, met = 0.0f;
    if (gmask > 0.0f && dan < gr) {
        int base = (b * NA + a) * 3;
        float px = pd_circles[base + 0];
        float py = pd_circles[base + 1];
        float pr = pd_circles[base + 2];
        float iou = circle_iou(gx, gy, gr, px, py, pr);
        ov = iou * gmask;
        float sc = pd_scores[(size_t)(b * NA + a) * NC + gl] * gmask;
        float o2 = ov * ov;
        met = sc * (o2 * o2 * o2);              // score^1 * ov^6
    }
    *ov_out = ov; *met_out = met;
}

// ---------------------------------------------------------------- K0 init

__global__ void k_init(int* __restrict__ fg_count, int* __restrict__ sel_m,
                       int* __restrict__ pos_align_i, int* __restrict__ pos_ov_i) {
    int i = blockIdx.x * blockDim.x + threadIdx.x;
    if (i < B * NA) { fg_count[i] = 0; sel_m[i] = 0x7fffffff; }
    if (i < B * M)  { pos_align_i[i] = 0; pos_ov_i[i] = 0; }
}

// ---------------------------------------------------------------- K1: per-(b,m) compact + metric + top-13 + scatter
// 1024 threads: full-occupancy scan; selection on wave 0 with zero barriers.

__global__ __launch_bounds__(TPB)
void k_topk3(const float* __restrict__ pd_scores, const float* __restrict__ pd_circles,
             const float* __restrict__ anc, const int* __restrict__ gt_labels,
             const float* __restrict__ gt_circles, const float* __restrict__ mask_gt,
             int* __restrict__ fg_count, int* __restrict__ sel_m) {
    int bm = blockIdx.x;
    int b  = bm / M;
    int m  = bm - b * M;
    int tid = threadIdx.x;

    __shared__ int   s_cnt, s_pcnt;
    __shared__ int   s_a[NPOS];     // in-circle anchors
    __shared__ int   s_pa[NPOS];    // positive-metric anchors
    __shared__ float s_pv[NPOS];    // their metrics
    __shared__ int   s_win[KK];

    float gmask = mask_gt[bm];
    if (!(gmask > 0.0f)) return;               // inactive gt contributes nothing

    float gx = gt_circles[bm * 3 + 0];
    float gy = gt_circles[bm * 3 + 1];
    float gr = gt_circles[bm * 3 + 2];
    int gl = gt_labels[bm];
    gl = gl < 0 ? 0 : (gl > NC - 1 ? NC - 1 : gl);

    if (tid == 0) { s_cnt = 0; s_pcnt = 0; }
    __syncthreads();

    // phase A: distance-only scan, 2 anchors per thread-iteration (float4)
    for (int q = tid; q < NA / 2; q += TPB) {
        float4 p = reinterpret_cast<const float4*>(anc)[q];
        float dx0 = p.x - gx, dy0 = p.y - gy;
        float dx1 = p.z - gx, dy1 = p.w - gy;
        bool h0 = sqrtf(dx0 * dx0 + dy0 * dy0) < gr;
        bool h1 = sqrtf(dx1 * dx1 + dy1 * dy1) < gr;
        if (h0) { int p0 = atomicAdd(&s_cnt, 1); if (p0 < NPOS) s_a[p0] = 2 * q; }
        if (h1) { int p1 = atomicAdd(&s_cnt, 1); if (p1 < NPOS) s_a[p1] = 2 * q + 1; }
    }
    __syncthreads();
    int cnt = s_cnt; if (cnt > NPOS) cnt = NPOS;

    // phase B: dense metric over in-circle candidates; keep positives only
    for (int i = tid; i < cnt; i += TPB) {
        int a = s_a[i];
        int base = (b * NA + a) * 3;
        float px = pd_circles[base + 0];
        float py = pd_circles[base + 1];
        float pr = pd_circles[base + 2];
        float iou = circle_iou(gx, gy, gr, px, py, pr);
        float ov = iou * gmask;
        float sc = pd_scores[(size_t)(b * NA + a) * NC + gl] * gmask;
        float o2 = ov * ov;
        float met = sc * (o2 * o2 * o2);
        if (met > 0.0f) {
            int pp = atomicAdd(&s_pcnt, 1);    // pp < cnt <= NPOS guaranteed
            s_pa[pp] = a; s_pv[pp] = met;
        }
    }
    __syncthreads();

    if (tid >= 64) return;                     // selection: wave 0 only, no barriers below

    int pcnt = s_pcnt;

    // 13 rounds of argmax (val desc, anchor asc) == lax.top_k order
    for (int k = 0; k < KK; k++) {
        float bv = 0.0f; int ba = 0x7fffffff; int bp = -1;
        for (int i = tid; i < pcnt; i += 64) {
            float v = s_pv[i];
            int   a = s_pa[i];
            if (v > bv || (v == bv && v > 0.0f && a < ba)) { bv = v; ba = a; bp = i; }
        }
        for (int off = 32; off > 0; off >>= 1) {
            float v2 = __shfl_xor(bv, off);
            int   a2 = __shfl_xor(ba, off);
            int   p2 = __shfl_xor(bp, off);
            if (v2 > bv || (v2 == bv && a2 < ba)) { bv = v2; ba = a2; bp = p2; }
        }
        // all lanes agree on (bv, ba, bp)
        if (tid == 0) {
            if (bp >= 0) { s_win[k] = ba; s_pv[bp] = -1.0f; }
            else s_win[k] = -2;
        }
    }

    // zero-fill: top_k ties at 0 -> lowest anchor indices with metric == 0.
    // wave-parallel: 64 anchors per chunk, ballot, take lowest set bits.
    int defmask = 0;
    for (int k = 0; k < KK; k++) if (s_win[k] == -2) defmask |= (1 << k);
    if (defmask) {
        int astart = 0;
        while (defmask && astart < NA) {
            int a = astart + tid;
            bool zero = false;
            if (a < NA) {
                float ov, met;
                ov_met(pd_scores, pd_circles, anc, b, a, gx, gy, gr, gl, gmask, &ov, &met);
                zero = !(met > 0.0f);
            }
            unsigned long long msk = __ballot(zero);
            while (msk && defmask) {
                int bit = __ffsll((long long)msk) - 1; msk &= msk - 1;
                int k2  = __ffs(defmask) - 1;          defmask &= defmask - 1;
                if (tid == 0) s_win[k2] = astart + bit;
            }
            astart += 64;
        }
        while (defmask) {                       // no zeros left (practically impossible)
            int k2 = __ffs(defmask) - 1; defmask &= defmask - 1;
            if (tid == 0) s_win[k2] = -1;
        }
    }

    // winners enter mask_pos only if anchor center inside the gt circle; scatter
    if (tid < KK) {
        int a = s_win[tid];
        if (a >= 0) {
            float ax = anc[2 * a], ay = anc[2 * a + 1];
            float dx = ax - gx, dy = ay - gy;
            if (sqrtf(dx * dx + dy * dy) < gr) {
                atomicAdd(&fg_count[b * NA + a], 1);
                atomicMin(&sel_m[b * NA + a], m);
            }
        }
    }
}

// ---------------------------------------------------------------- K2 fused: per-anchor resolve + pos maxima

__global__ void k_resolve_posmax(const float* __restrict__ pd_scores,
                                 const float* __restrict__ pd_circles, const float* __restrict__ anc,
                                 const int* __restrict__ gt_labels, const float* __restrict__ gt_circles,
                                 const float* __restrict__ mask_gt,
                                 const int* __restrict__ fg_count, const int* __restrict__ sel_m,
                                 int* __restrict__ assigned, float* __restrict__ am_val,
                                 int* __restrict__ pos_align_i, int* __restrict__ pos_ov_i,
                                 float* __restrict__ out_labels, float* __restrict__ out_circles,
                                 float* __restrict__ out_fg, float* __restrict__ out_gtidx) {
    int i = blockIdx.x * blockDim.x + threadIdx.x;
    if (i >= B * NA) return;
    int b = i / NA, a = i - b * NA;
    int c = fg_count[i];
    int g = 0, fg = 0;
    if (c == 1) { g = sel_m[i]; fg = 1; }
    else if (c > 1) {
        // jnp.argmax over masked overlaps, lowest index wins ties
        float ax = anc[2 * a], ay = anc[2 * a + 1];
        int pbase = i * 3;
        float px = pd_circles[pbase], py = pd_circles[pbase + 1], pr = pd_circles[pbase + 2];
        float best = -1.0f; int bmx = 0;
        for (int mm = 0; mm < M; mm++) {
            float gmask = mask_gt[b * M + mm];
            float gx = gt_circles[(b * M + mm) * 3 + 0];
            float gy = gt_circles[(b * M + mm) * 3 + 1];
            float grr = gt_circles[(b * M + mm) * 3 + 2];
            float dx = ax - gx, dy = ay - gy;
            float ov = 0.0f;
            if (gmask > 0.0f && sqrtf(dx * dx + dy * dy) < grr)
                ov = circle_iou(gx, gy, grr, px, py, pr) * gmask;
            if (ov > best) { best = ov; bmx = mm; }
        }
        g = bmx; fg = 1;
    }
    assigned[i] = fg ? g : -1;
    int lbl = gt_labels[b * M + g]; if (lbl < 0) lbl = 0;   // clip(.., 0, None)
    out_labels[i] = (float)lbl;
    out_circles[(size_t)i * 3 + 0] = gt_circles[(b * M + g) * 3 + 0];
    out_circles[(size_t)i * 3 + 1] = gt_circles[(b * M + g) * 3 + 1];
    out_circles[(size_t)i * 3 + 2] = gt_circles[(b * M + g) * 3 + 2];
    out_fg[i]    = fg ? 1.0f : 0.0f;
    out_gtidx[i] = (float)g;

    if (!fg) { am_val[i] = 0.0f; return; }
    float gmask = mask_gt[b * M + g];
    float gx = gt_circles[(b * M + g) * 3 + 0];
    float gy = gt_circles[(b * M + g) * 3 + 1];
    float grc = gt_circles[(b * M + g) * 3 + 2];
    int gl2 = gt_labels[b * M + g];
    gl2 = gl2 < 0 ? 0 : (gl2 > NC - 1 ? NC - 1 : gl2);
    float ov, met;
    ov_met(pd_scores, pd_circles, anc, b, a, gx, gy, grc, gl2, gmask, &ov, &met);
    am_val[i] = met;
    atomicMax(&pos_align_i[b * M + g], __float_as_int(met));  // values >= 0
    atomicMax(&pos_ov_i[b * M + g],    __float_as_int(ov));
}

// ---------------------------------------------------------------- K3 target_scores (86 MB write)

__global__ void k_scores(const int* __restrict__ assigned, const float* __restrict__ am_val,
                         const int* __restrict__ pos_align_i, const int* __restrict__ pos_ov_i,
                         const int* __restrict__ gt_labels,
                         float* __restrict__ out_scores) {
    int q = blockIdx.x * blockDim.x + threadIdx.x;      // one float4 per thread
    if (q >= (B * NA * NC) / 4) return;
    int idx = q * 4;
    int row = idx / NC;
    int c0  = idx - row * NC;
    float4 v = make_float4(0.f, 0.f, 0.f, 0.f);
    int g = assigned[row];
    if (g >= 0) {
        int b = row / NA;
        float pa = __int_as_float(pos_align_i[b * M + g]);
        float po = __int_as_float(pos_ov_i[b * M + g]);
        float norm = am_val[row] * po / (pa + EPSF);
        int lbl = gt_labels[b * M + g]; if (lbl < 0) lbl = 0;
        int off = lbl - c0;
        if (off >= 0 && off < 4) ((float*)&v)[off] = norm;
    }
    reinterpret_cast<float4*>(out_scores)[q] = v;
}

// ---------------------------------------------------------------- launch

extern "C" void kernel_launch(void* const* d_in, const int* in_sizes, int n_in,
                              void* d_out, int out_size, void* d_ws, size_t ws_size,
                              hipStream_t stream) {
    const float* pd_scores  = (const float*)d_in[0];   // (B, NA, NC)
    const float* pd_circles = (const float*)d_in[1];   // (B, NA, 3)
    const float* anc        = (const float*)d_in[2];   // (NA, 2)
    const int*   gt_labels  = (const int*)  d_in[3];   // (B, M, 1)
    const float* gt_circles = (const float*)d_in[4];   // (B, M, 3)
    const float* mask_gt    = (const float*)d_in[5];   // (B, M, 1)

    // workspace layout
    char* w = (char*)d_ws;
    int*   fg_count    = (int*)w;   w += (size_t)B * NA * sizeof(int);
    int*   sel_m       = (int*)w;   w += (size_t)B * NA * sizeof(int);
    int*   assigned    = (int*)w;   w += (size_t)B * NA * sizeof(int);
    float* am_val      = (float*)w; w += (size_t)B * NA * sizeof(float);
    int*   pos_align_i = (int*)w;   w += (size_t)B * M * sizeof(int);
    int*   pos_ov_i    = (int*)w;   w += (size_t)B * M * sizeof(int);

    // output layout (concat in return order, float32)
    float* out        = (float*)d_out;
    float* out_labels = out;                              // B*NA
    float* out_circ   = out_labels + (size_t)B * NA;      // B*NA*3
    float* out_scores = out_circ + (size_t)B * NA * 3;    // B*NA*NC
    float* out_fg     = out_scores + (size_t)B * NA * NC; // B*NA
    float* out_gtidx  = out_fg + (size_t)B * NA;          // B*NA

    const int T = 256;
    int gBA = (B * NA + T - 1) / T;

    k_init<<<gBA, T, 0, stream>>>(fg_count, sel_m, pos_align_i, pos_ov_i);

    k_topk3<<<B * M, TPB, 0, stream>>>(pd_scores, pd_circles, anc, gt_labels,
                                       gt_circles, mask_gt, fg_count, sel_m);

    k_resolve_posmax<<<gBA, T, 0, stream>>>(pd_scores, pd_circles, anc, gt_labels,
                                            gt_circles, mask_gt, fg_count, sel_m,
                                            assigned, am_val, pos_align_i, pos_ov_i,
                                            out_labels, out_circ, out_fg, out_gtidx);

    int nq = (B * NA * NC) / 4;
    k_scores<<<(nq + T - 1) / T, T, 0, stream>>>(assigned, am_val, pos_align_i, pos_ov_i,
                                                 gt_labels, out_scores);
}

// Round 5
// 100.290 us; speedup vs baseline: 2.1709x; 1.0507x over previous
//
#include <hip/hip_runtime.h>
#include <math.h>

#define B   8
#define NA  33600
#define M   64
#define NC  80
#define KK  13
#define EPSF 1e-9f
#define PIF 3.14159265358979323846f

#define PCAP 1536          // per-(b,m) positive-metric capacity (max in-circle ~1100)

// ---------------------------------------------------------------- helpers

__device__ __forceinline__ float circle_iou(float gx, float gy, float gr,
                                            float px, float py, float pr) {
    float dx = gx - px, dy = gy - py;
    float d  = sqrtf(dx * dx + dy * dy + 1e-12f);
    float r0sq = gr * gr, r1sq = pr * pr;
    float d1 = (r0sq - r1sq + d * d) / (2.0f * d);
    float d2 = d - d1;
    float t0 = fminf(fmaxf(d1 / fmaxf(gr, EPSF), -1.0f), 1.0f);
    float t1 = fminf(fmaxf(d2 / fmaxf(pr, EPSF), -1.0f), 1.0f);
    float a0 = r0sq * acosf(t0) - d1 * sqrtf(fmaxf(r0sq - d1 * d1, 0.0f));
    float a1 = r1sq * acosf(t1) - d2 * sqrtf(fmaxf(r1sq - d2 * d2, 0.0f));
    float lens = a0 + a1;
    float rmin = fminf(gr, pr);
    float contained = PIF * rmin * rmin;
    float inter = (d >= gr + pr) ? 0.0f
                : ((d <= fabsf(gr - pr)) ? contained : lens);
    float uni = PIF * r0sq + PIF * r1sq - inter;
    return (uni > 0.0f) ? inter / uni : 0.0f;
}

// masked overlap + align_metric for one (b, gt, anchor) — reference formula
__device__ __forceinline__ void ov_met(const float* __restrict__ pd_scores,
                                       const float* __restrict__ pd_circles,
                                       const float* __restrict__ anc,
                                       int b, int a,
                                       float gx, float gy, float gr, int gl, float gmask,
                                       float* ov_out, float* met_out) {
    float ax = anc[2 * a], ay = anc[2 * a + 1];
    float dx = ax - gx, dy = ay - gy;
    float dan = sqrtf(dx * dx + dy * dy);
    float ov = 0.0f, met = 0.0f;
    if (gmask > 0.0f && dan < gr) {
        int base = (b * NA + a) * 3;
        float px = pd_circles[base + 0];
        float py = pd_circles[base + 1];
        float pr = pd_circles[base + 2];
        // cheap exact pre-test: d >= r0+r1  ->  inter = 0 -> iou = 0
        float cdx = gx - px, cdy = gy - py;
        float dc = sqrtf(cdx * cdx + cdy * cdy + 1e-12f);
        float iou = (dc >= gr + pr) ? 0.0f : circle_iou(gx, gy, gr, px, py, pr);
        ov = iou * gmask;
        if (ov > 0.0f) {
            float sc = pd_scores[(size_t)(b * NA + a) * NC + gl] * gmask;
            float o2 = ov * ov;
            met = sc * (o2 * o2 * o2);          // score^1 * ov^6
        }
    }
    *ov_out = ov; *met_out = met;
}

// ---------------------------------------------------------------- K0 init

__global__ void k_init(int* __restrict__ fg_count, int* __restrict__ sel_m,
                       int* __restrict__ pos_align_i, int* __restrict__ pos_ov_i,
                       int* __restrict__ plist_cnt) {
    int i = blockIdx.x * blockDim.x + threadIdx.x;
    if (i < B * NA) { fg_count[i] = 0; sel_m[i] = 0x7fffffff; }
    if (i < B * M)  { pos_align_i[i] = 0; pos_ov_i[i] = 0; plist_cnt[i] = 0; }
}

// ---------------------------------------------------------------- K1: per-anchor dense pass
// one thread per (b,a): coalesced pd_circles read, 64 gts from LDS, append
// positive-metric pairs to per-(b,m) global lists (~3K appends total).

__global__ __launch_bounds__(256)
void k_build(const float* __restrict__ pd_scores, const float* __restrict__ pd_circles,
             const float* __restrict__ anc, const int* __restrict__ gt_labels,
             const float* __restrict__ gt_circles, const float* __restrict__ mask_gt,
             int* __restrict__ plist_cnt, int* __restrict__ plist_a,
             float* __restrict__ plist_v) {
    int b = blockIdx.y;
    __shared__ float s_gx[M], s_gy[M], s_gr[M];
    __shared__ int   s_gl[M], s_act[M];
    if (threadIdx.x < M) {
        int gi = b * M + threadIdx.x;
        s_act[threadIdx.x] = mask_gt[gi] > 0.0f;
        s_gx[threadIdx.x] = gt_circles[gi * 3 + 0];
        s_gy[threadIdx.x] = gt_circles[gi * 3 + 1];
        s_gr[threadIdx.x] = gt_circles[gi * 3 + 2];
        int l = gt_labels[gi];
        s_gl[threadIdx.x] = l < 0 ? 0 : (l > NC - 1 ? NC - 1 : l);
    }
    __syncthreads();

    int a = blockIdx.x * 256 + threadIdx.x;
    if (a >= NA) return;
    float2 ap = reinterpret_cast<const float2*>(anc)[a];
    int base = (b * NA + a) * 3;
    float px = pd_circles[base + 0];       // dense coalesced stream
    float py = pd_circles[base + 1];
    float pr = pd_circles[base + 2];

    for (int m = 0; m < M; m++) {
        if (!s_act[m]) continue;           // wave-uniform
        float gx = s_gx[m], gy = s_gy[m], gr = s_gr[m];
        float dxa = ap.x - gx, dya = ap.y - gy;
        if (!(sqrtf(dxa * dxa + dya * dya) < gr)) continue;   // in-circle?
        // exact pre-test: non-intersecting circles -> iou = 0 -> met = 0
        float cdx = gx - px, cdy = gy - py;
        float dc = sqrtf(cdx * cdx + cdy * cdy + 1e-12f);
        if (dc >= gr + pr) continue;
        float ov = circle_iou(gx, gy, gr, px, py, pr);        // * gmask(==1)
        if (!(ov > 0.0f)) continue;
        float sc = pd_scores[(size_t)(b * NA + a) * NC + s_gl[m]];
        float o2 = ov * ov;
        float met = sc * (o2 * o2 * o2);
        if (met > 0.0f) {
            int bm = b * M + m;
            int p = atomicAdd(&plist_cnt[bm], 1);
            if (p < PCAP) { plist_a[bm * PCAP + p] = a; plist_v[bm * PCAP + p] = met; }
        }
    }
}

// ---------------------------------------------------------------- K2: per-(b,m) top-13 select + scatter
// one wave per (b,m); list is tiny (~6 positives typically).

__global__ __launch_bounds__(64)
void k_select(const float* __restrict__ pd_scores, const float* __restrict__ pd_circles,
              const float* __restrict__ anc, const int* __restrict__ gt_labels,
              const float* __restrict__ gt_circles, const float* __restrict__ mask_gt,
              const int* __restrict__ plist_cnt, const int* __restrict__ plist_a,
              const float* __restrict__ plist_v,
              int* __restrict__ fg_count, int* __restrict__ sel_m) {
    int bm = blockIdx.x;
    int b  = bm / M;
    int m  = bm - b * M;
    int tid = threadIdx.x;

    __shared__ int   s_a[PCAP];
    __shared__ float s_v[PCAP];
    __shared__ int   s_win[KK];

    float gmask = mask_gt[bm];
    if (!(gmask > 0.0f)) return;

    float gx = gt_circles[bm * 3 + 0];
    float gy = gt_circles[bm * 3 + 1];
    float gr = gt_circles[bm * 3 + 2];
    int gl = gt_labels[bm];
    gl = gl < 0 ? 0 : (gl > NC - 1 ? NC - 1 : gl);

    int pcnt = plist_cnt[bm]; if (pcnt > PCAP) pcnt = PCAP;
    for (int i = tid; i < pcnt; i += 64) {
        s_a[i] = plist_a[bm * PCAP + i];
        s_v[i] = plist_v[bm * PCAP + i];
    }
    __syncthreads();

    // 13 rounds of argmax (val desc, anchor asc) == lax.top_k order
    for (int k = 0; k < KK; k++) {
        float bv = 0.0f; int ba = 0x7fffffff; int bp = -1;
        for (int i = tid; i < pcnt; i += 64) {
            float v = s_v[i];
            if (v > 0.0f) {
                int a = s_a[i];
                if (v > bv || (v == bv && a < ba)) { bv = v; ba = a; bp = i; }
            }
        }
        for (int off = 32; off > 0; off >>= 1) {
            float v2 = __shfl_xor(bv, off);
            int   a2 = __shfl_xor(ba, off);
            int   p2 = __shfl_xor(bp, off);
            if (v2 > bv || (v2 == bv && a2 < ba)) { bv = v2; ba = a2; bp = p2; }
        }
        if (tid == 0) {
            if (bp >= 0) { s_win[k] = ba; s_v[bp] = -1.0f; }
            else s_win[k] = -2;
        }
    }

    // zero-fill: top_k ties at 0 -> lowest anchor indices with metric == 0
    int defmask = 0;
    for (int k = 0; k < KK; k++) if (s_win[k] == -2) defmask |= (1 << k);
    if (defmask) {
        int astart = 0;
        while (defmask && astart < NA) {
            int a = astart + tid;
            bool zero = false;
            if (a < NA) {
                float ov, met;
                ov_met(pd_scores, pd_circles, anc, b, a, gx, gy, gr, gl, gmask, &ov, &met);
                zero = !(met > 0.0f);
            }
            unsigned long long msk = __ballot(zero);
            while (msk && defmask) {
                int bit = __ffsll((long long)msk) - 1; msk &= msk - 1;
                int k2  = __ffs(defmask) - 1;          defmask &= defmask - 1;
                if (tid == 0) s_win[k2] = astart + bit;
            }
            astart += 64;
        }
        while (defmask) {
            int k2 = __ffs(defmask) - 1; defmask &= defmask - 1;
            if (tid == 0) s_win[k2] = -1;
        }
    }

    // winners enter mask_pos only if anchor center inside the gt circle; scatter
    if (tid < KK) {
        int a = s_win[tid];
        if (a >= 0) {
            float ax = anc[2 * a], ay = anc[2 * a + 1];
            float dx = ax - gx, dy = ay - gy;
            if (sqrtf(dx * dx + dy * dy) < gr) {
                atomicAdd(&fg_count[b * NA + a], 1);
                atomicMin(&sel_m[b * NA + a], m);
            }
        }
    }
}

// ---------------------------------------------------------------- K3 fused: per-anchor resolve + pos maxima

__global__ void k_resolve_posmax(const float* __restrict__ pd_scores,
                                 const float* __restrict__ pd_circles, const float* __restrict__ anc,
                                 const int* __restrict__ gt_labels, const float* __restrict__ gt_circles,
                                 const float* __restrict__ mask_gt,
                                 const int* __restrict__ fg_count, const int* __restrict__ sel_m,
                                 int* __restrict__ assigned, float* __restrict__ am_val,
                                 int* __restrict__ pos_align_i, int* __restrict__ pos_ov_i,
                                 float* __restrict__ out_labels, float* __restrict__ out_circles,
                                 float* __restrict__ out_fg, float* __restrict__ out_gtidx) {
    int i = blockIdx.x * blockDim.x + threadIdx.x;
    if (i >= B * NA) return;
    int b = i / NA, a = i - b * NA;
    int c = fg_count[i];
    int g = 0, fg = 0;
    if (c == 1) { g = sel_m[i]; fg = 1; }
    else if (c > 1) {
        // jnp.argmax over masked overlaps, lowest index wins ties
        float ax = anc[2 * a], ay = anc[2 * a + 1];
        int pbase = i * 3;
        float px = pd_circles[pbase], py = pd_circles[pbase + 1], pr = pd_circles[pbase + 2];
        float best = -1.0f; int bmx = 0;
        for (int mm = 0; mm < M; mm++) {
            float gmask = mask_gt[b * M + mm];
            float gx = gt_circles[(b * M + mm) * 3 + 0];
            float gy = gt_circles[(b * M + mm) * 3 + 1];
            float grr = gt_circles[(b * M + mm) * 3 + 2];
            float dx = ax - gx, dy = ay - gy;
            float ov = 0.0f;
            if (gmask > 0.0f && sqrtf(dx * dx + dy * dy) < grr)
                ov = circle_iou(gx, gy, grr, px, py, pr) * gmask;
            if (ov > best) { best = ov; bmx = mm; }
        }
        g = bmx; fg = 1;
    }
    assigned[i] = fg ? g : -1;
    int lbl = gt_labels[b * M + g]; if (lbl < 0) lbl = 0;   // clip(.., 0, None)
    out_labels[i] = (float)lbl;
    out_circles[(size_t)i * 3 + 0] = gt_circles[(b * M + g) * 3 + 0];
    out_circles[(size_t)i * 3 + 1] = gt_circles[(b * M + g) * 3 + 1];
    out_circles[(size_t)i * 3 + 2] = gt_circles[(b * M + g) * 3 + 2];
    out_fg[i]    = fg ? 1.0f : 0.0f;
    out_gtidx[i] = (float)g;

    if (!fg) { am_val[i] = 0.0f; return; }
    float gmask = mask_gt[b * M + g];
    float gx = gt_circles[(b * M + g) * 3 + 0];
    float gy = gt_circles[(b * M + g) * 3 + 1];
    float grc = gt_circles[(b * M + g) * 3 + 2];
    int gl2 = gt_labels[b * M + g];
    gl2 = gl2 < 0 ? 0 : (gl2 > NC - 1 ? NC - 1 : gl2);
    float ov, met;
    ov_met(pd_scores, pd_circles, anc, b, a, gx, gy, grc, gl2, gmask, &ov, &met);
    am_val[i] = met;
    atomicMax(&pos_align_i[b * M + g], __float_as_int(met));  // values >= 0
    atomicMax(&pos_ov_i[b * M + g],    __float_as_int(ov));
}

// ---------------------------------------------------------------- K4 target_scores (86 MB write)

__global__ void k_scores(const int* __restrict__ assigned, const float* __restrict__ am_val,
                         const int* __restrict__ pos_align_i, const int* __restrict__ pos_ov_i,
                         const int* __restrict__ gt_labels,
                         float* __restrict__ out_scores) {
    int q = blockIdx.x * blockDim.x + threadIdx.x;      // one float4 per thread
    if (q >= (B * NA * NC) / 4) return;
    int idx = q * 4;
    int row = idx / NC;
    int c0  = idx - row * NC;
    float4 v = make_float4(0.f, 0.f, 0.f, 0.f);
    int g = assigned[row];
    if (g >= 0) {
        int b = row / NA;
        float pa = __int_as_float(pos_align_i[b * M + g]);
        float po = __int_as_float(pos_ov_i[b * M + g]);
        float norm = am_val[row] * po / (pa + EPSF);
        int lbl = gt_labels[b * M + g]; if (lbl < 0) lbl = 0;
        int off = lbl - c0;
        if (off >= 0 && off < 4) ((float*)&v)[off] = norm;
    }
    reinterpret_cast<float4*>(out_scores)[q] = v;
}

// ---------------------------------------------------------------- launch

extern "C" void kernel_launch(void* const* d_in, const int* in_sizes, int n_in,
                              void* d_out, int out_size, void* d_ws, size_t ws_size,
                              hipStream_t stream) {
    const float* pd_scores  = (const float*)d_in[0];   // (B, NA, NC)
    const float* pd_circles = (const float*)d_in[1];   // (B, NA, 3)
    const float* anc        = (const float*)d_in[2];   // (NA, 2)
    const int*   gt_labels  = (const int*)  d_in[3];   // (B, M, 1)
    const float* gt_circles = (const float*)d_in[4];   // (B, M, 3)
    const float* mask_gt    = (const float*)d_in[5];   // (B, M, 1)

    // workspace layout
    char* w = (char*)d_ws;
    int*   plist_cnt   = (int*)w;   w += (size_t)B * M * sizeof(int);
    int*   plist_a     = (int*)w;   w += (size_t)B * M * PCAP * sizeof(int);
    float* plist_v     = (float*)w; w += (size_t)B * M * PCAP * sizeof(float);
    int*   fg_count    = (int*)w;   w += (size_t)B * NA * sizeof(int);
    int*   sel_m       = (int*)w;   w += (size_t)B * NA * sizeof(int);
    int*   assigned    = (int*)w;   w += (size_t)B * NA * sizeof(int);
    float* am_val      = (float*)w; w += (size_t)B * NA * sizeof(float);
    int*   pos_align_i = (int*)w;   w += (size_t)B * M * sizeof(int);
    int*   pos_ov_i    = (int*)w;   w += (size_t)B * M * sizeof(int);

    // output layout (concat in return order, float32)
    float* out        = (float*)d_out;
    float* out_labels = out;                              // B*NA
    float* out_circ   = out_labels + (size_t)B * NA;      // B*NA*3
    float* out_scores = out_circ + (size_t)B * NA * 3;    // B*NA*NC
    float* out_fg     = out_scores + (size_t)B * NA * NC; // B*NA
    float* out_gtidx  = out_fg + (size_t)B * NA;          // B*NA

    const int T = 256;
    int gBA = (B * NA + T - 1) / T;

    k_init<<<gBA, T, 0, stream>>>(fg_count, sel_m, pos_align_i, pos_ov_i, plist_cnt);

    dim3 gb((NA + 255) / 256, B);
    k_build<<<gb, 256, 0, stream>>>(pd_scores, pd_circles, anc, gt_labels,
                                    gt_circles, mask_gt, plist_cnt, plist_a, plist_v);

    k_select<<<B * M, 64, 0, stream>>>(pd_scores, pd_circles, anc, gt_labels,
                                       gt_circles, mask_gt, plist_cnt, plist_a, plist_v,
                                       fg_count, sel_m);

    k_resolve_posmax<<<gBA, T, 0, stream>>>(pd_scores, pd_circles, anc, gt_labels,
                                            gt_circles, mask_gt, fg_count, sel_m,
                                            assigned, am_val, pos_align_i, pos_ov_i,
                                            out_labels, out_circ, out_fg, out_gtidx);

    int nq = (B * NA * NC) / 4;
    k_scores<<<(nq + T - 1) / T, T, 0, stream>>>(assigned, am_val, pos_align_i, pos_ov_i,
                                                 gt_labels, out_scores);
}